// Round 1
// baseline (385.723 us; speedup 1.0000x reference)
//
#include <hip/hip_runtime.h>
#include <cfloat>
#include <cmath>

#define HH   2048
#define ISZ  4096
#define WN   10
#define ND   6
#define EPSF 1e-9f

// ---- workspace layout (float offsets), total ~1.39 MB ----
#define O_WROW   0          // 7*2048 row-weight vectors for stack rowsums
#define O_GETW   14336      // 5*16  get weights (ip[0..9] at step t)
#define O_POPC   14464      // 6*4   pop correction coefficients
#define O_AVAIL  14496      // 6
#define O_SCAL   14528      // [0:6] perp_pred [6:12] gate1 [12:18] perp [18:24] w
#define O_IPTR   14592      // 6*16  ip trajectory
#define O_DFIN   14720      // 6*2048 final diag per depth
#define O_CNEW   27008      // 6*2048 new_inp push coeff per depth
#define O_CFIN   39296      // 6*4*2048 g-term coeffs per depth
#define O_SPTR   88448      // 6*2048 final stack pointers
#define O_MW     100736     // 2048 combined diag
#define O_CEFF   104832     // 2048*10 combined rank-1 coeffs
#define O_R      125312     // 7*4096 stack rowsums
#define O_NEWINP 153984     // 6*4096 (V rows 0..5)
#define O_G      178560     // 5*4096 (V rows 6..9; MUST be O_NEWINP+6*ISZ)
#define O_HVEC   199040     // 6*4096
#define O_IVEC   223616     // 6*4096
#define O_YFF    248192     // 6*4096
#define O_Z      272768     // 6*4096
#define O_YH     297344     // 6*4096
#define O_YI     321920     // 6*4096

__device__ __forceinline__ float waveReduceSum(float v){
  #pragma unroll
  for (int o=32;o>0;o>>=1) v += __shfl_down(v,o);
  return __shfl(v,0);
}

__device__ __forceinline__ float blockReduceSum(float v, float* sm){
  int ln = threadIdx.x & 63, w = threadIdx.x >> 6;
  #pragma unroll
  for (int o=32;o>0;o>>=1) v += __shfl_down(v,o);
  if (ln==0) sm[w]=v;
  __syncthreads();
  if (threadIdx.x==0){
    float r=0.f; int nw=(int)(blockDim.x>>6);
    for (int i=0;i<nw;i++) r+=sm[i];
    sm[16]=r;
  }
  __syncthreads();
  float r = sm[16];
  __syncthreads();
  return r;
}

__device__ __forceinline__ float blockReduceMax(float v, float* sm){
  int ln = threadIdx.x & 63, w = threadIdx.x >> 6;
  #pragma unroll
  for (int o=32;o>0;o>>=1) v = fmaxf(v,__shfl_down(v,o));
  if (ln==0) sm[w]=v;
  __syncthreads();
  if (threadIdx.x==0){
    float r=-FLT_MAX; int nw=(int)(blockDim.x>>6);
    for (int i=0;i<nw;i++) r=fmaxf(r,sm[i]);
    sm[16]=r;
  }
  __syncthreads();
  float r = sm[16];
  __syncthreads();
  return r;
}

// ---------------------------------------------------------------------------
// K1: all pointer algebra (data-independent). Single wave.
// ---------------------------------------------------------------------------
__global__ __launch_bounds__(64) void k_ptr_prep(
    const float* __restrict__ sp0g, const float* __restrict__ ip0g,
    float* __restrict__ ws)
{
  __shared__ float sp[HH], q[HH], D[HH], tmp[HH];
  __shared__ float c[4][HH];
  const int ln = threadIdx.x;

  float* Wrow = ws + O_WROW;
  float* getW = ws + O_GETW;
  float* popc = ws + O_POPC;
  float* Dfin = ws + O_DFIN;
  float* cnew = ws + O_CNEW;
  float* cfin = ws + O_CFIN;
  float* sptr = ws + O_SPTR;
  float* iptr = ws + O_IPTR;
  float* avail= ws + O_AVAIL;

  // input-pointer trajectory (11 wide)
  if (ln==0){
    float ip[WN+1], nip[WN+1];
    for (int k=0;k<=WN;k++) ip[k]=ip0g[k];
    for (int k=0;k<=WN;k++) iptr[k]=ip[k];
    avail[0] = 1.f - ip[WN];
    for (int t=0;t<5;t++){
      for (int k=0;k<WN;k++) getW[t*16+k]=ip[k];
      nip[0]=0.f;
      for (int k=1;k<=WN;k++) nip[k]=ip[k-1];
      nip[WN] += ip[WN];
      for (int k=0;k<=WN;k++) ip[k]=nip[k];
      for (int k=0;k<=WN;k++) iptr[(t+1)*16+k]=ip[k];
      avail[t+1] = 1.f - ip[WN];
    }
  }

  // ---------- depth 0: pop,pop,push ----------
  for (int j=ln;j<HH;j+=64) sp[j]=sp0g[j];
  __syncthreads();
  for (int j=ln;j<HH;j+=64) q[j] = (j<HH-1)? sp[j+1] : 0.f;
  __syncthreads();
  float s=0.f;
  for (int j=ln;j<HH;j+=64) s += q[j];
  s = waveReduceSum(s);
  float sc = (s>0.f)? 1.f/s : 1.f;
  for (int j=ln;j<HH;j+=64){ Wrow[j] = q[j]*sc; D[j] = 1.f - q[j]; }
  {
    float spo = sp[0];
    __syncthreads();
    for (int j=ln;j<HH;j+=64) tmp[j] = q[j] + ((j==0)? spo : 0.f);
    __syncthreads();
    for (int j=ln;j<HH;j+=64) sp[j]=tmp[j];
    __syncthreads();
  }
  for (int j=ln;j<HH;j+=64) q[j] = (j<HH-1)? sp[j+1] : 0.f;
  __syncthreads();
  s=0.f; for (int j=ln;j<HH;j+=64) s += q[j];
  s = waveReduceSum(s);
  sc = (s>0.f)? 1.f/s : 1.f;
  for (int j=ln;j<HH;j+=64){ Wrow[HH+j] = q[j]*sc*D[j]; D[j] *= (1.f - q[j]); }
  {
    float spo = sp[0];
    __syncthreads();
    for (int j=ln;j<HH;j+=64) tmp[j] = q[j] + ((j==0)? spo : 0.f);
    __syncthreads();
    for (int j=ln;j<HH;j+=64) sp[j]=tmp[j];
    __syncthreads();
  }
  for (int j=ln;j<HH;j+=64){
    float p = sp[j];
    Dfin[j] = D[j]*(1.f-p);
    cnew[j] = p;
    sptr[j] = (j==0)? 0.f : sp[j-1];
  }
  __syncthreads();

  // ---------- depths 1..5 ----------
  for (int d=1; d<ND; d++){
    const int nterms = d-1;      // number of g-vector pushes before the pop
    for (int j=ln;j<HH;j+=64){ sp[j]=sp0g[j]; D[j]=1.f; }
    __syncthreads();
    for (int t=0;t<nterms;t++){
      for (int j=ln;j<HH;j+=64){
        float p = sp[j], f = 1.f-p;
        D[j] *= f;
        for (int u=0;u<t;u++) c[u][j] *= f;
        c[t][j] = p;
      }
      __syncthreads();
      for (int j=ln;j<HH;j+=64) tmp[j] = (j==0)? 0.f : sp[j-1];
      __syncthreads();
      for (int j=ln;j<HH;j+=64) sp[j]=tmp[j];
      __syncthreads();
    }
    // pop
    for (int j=ln;j<HH;j+=64) q[j] = (j<HH-1)? sp[j+1] : 0.f;
    __syncthreads();
    s=0.f; for (int j=ln;j<HH;j+=64) s += q[j];
    s = waveReduceSum(s);
    sc = (s>0.f)? 1.f/s : 1.f;
    for (int t=0;t<nterms;t++){
      float pc=0.f;
      for (int j=ln;j<HH;j+=64) pc += q[j]*sc*c[t][j];
      pc = waveReduceSum(pc);
      if (ln==0) popc[d*4+t]=pc;
    }
    for (int j=ln;j<HH;j+=64){
      float n = q[j]*sc;
      Wrow[(1+d)*HH+j] = n*D[j];
      float f = 1.f - q[j];
      D[j] *= f;
      for (int t=0;t<nterms;t++) c[t][j] *= f;
    }
    {
      float spo = sp[0];
      __syncthreads();
      for (int j=ln;j<HH;j+=64) tmp[j] = q[j] + ((j==0)? spo : 0.f);
      __syncthreads();
      for (int j=ln;j<HH;j+=64) sp[j]=tmp[j];
      __syncthreads();
    }
    // final push of new_inp_d
    for (int j=ln;j<HH;j+=64){
      float p = sp[j], f = 1.f-p;
      Dfin[d*HH+j] = D[j]*f;
      for (int t=0;t<nterms;t++) cfin[(d*4+t)*HH+j] = c[t][j]*f;
      cnew[d*HH+j] = p;
      sptr[d*HH+j] = (j==0)? 0.f : sp[j-1];
    }
    __syncthreads();
  }
}

// ---------------------------------------------------------------------------
// K2: R[k][col] = sum_j Wrow[k][j] * stack[j][col]  (7 weighted rowsums)
// ---------------------------------------------------------------------------
__global__ __launch_bounds__(256) void k_rowsum(
    const float* __restrict__ stk, const float* __restrict__ wrow,
    float* __restrict__ R)
{
  __shared__ float wsh[7][64];
  const int col = blockIdx.x*256 + threadIdx.x;
  const int r0  = blockIdx.y*64;
  for (int idx=threadIdx.x; idx<7*64; idx+=256){
    int k=idx>>6, r=idx&63;
    wsh[k][r]=wrow[k*HH + r0 + r];
  }
  __syncthreads();
  float a0=0,a1=0,a2=0,a3=0,a4=0,a5=0,a6=0;
  const float* sp = stk + (size_t)r0*ISZ + col;
  #pragma unroll 4
  for (int r=0;r<64;r++){
    float v = sp[(size_t)r*ISZ];
    a0+=wsh[0][r]*v; a1+=wsh[1][r]*v; a2+=wsh[2][r]*v; a3+=wsh[3][r]*v;
    a4+=wsh[4][r]*v; a5+=wsh[5][r]*v; a6+=wsh[6][r]*v;
  }
  atomicAdd(&R[0*ISZ+col],a0); atomicAdd(&R[1*ISZ+col],a1);
  atomicAdd(&R[2*ISZ+col],a2); atomicAdd(&R[3*ISZ+col],a3);
  atomicAdd(&R[4*ISZ+col],a4); atomicAdd(&R[5*ISZ+col],a5);
  atomicAdd(&R[6*ISZ+col],a6);
}

// g_t = getW[t][0..9] @ input  (5 vectors)
__global__ void k_gvec(const float* __restrict__ input,
                       const float* __restrict__ getW, float* __restrict__ g)
{
  int idx = blockIdx.x*256+threadIdx.x;
  if (idx >= 5*ISZ) return;
  int t = idx / ISZ, cx = idx % ISZ;
  float acc=0.f;
  #pragma unroll
  for (int k=0;k<WN;k++) acc += getW[t*16+k]*input[k*ISZ + cx];
  g[idx] = acc;
}

// Hvec/Ivec assembly
__global__ void k_build_hv(const float* __restrict__ R, const float* __restrict__ g,
                           const float* __restrict__ popc,
                           float* __restrict__ Hvec, float* __restrict__ Ivec)
{
  int idx = blockIdx.x*256+threadIdx.x;
  if (idx >= ND*ISZ) return;
  int d = idx/ISZ, cx = idx%ISZ;
  if (d==0){ Ivec[idx]=R[cx]; Hvec[idx]=R[ISZ+cx]; }
  else {
    Ivec[idx]=g[(d-1)*ISZ+cx];
    float h = R[(1+d)*ISZ+cx];
    for (int t=0;t<=d-2;t++) h += popc[d*4+t]*g[t*ISZ+cx];
    Hvec[idx]=h;
  }
}

// ---------------------------------------------------------------------------
// Batched (6-vector) matvec: Y[d][row] (+)= sum_k W[row][k]*X[d][k] + bias
// One row per wave, X staged in LDS (96 KB).
// ---------------------------------------------------------------------------
__global__ __launch_bounds__(1024) void k_matvec6(
    const float* __restrict__ W, int ldw,
    const float* __restrict__ X, const float* __restrict__ bias,
    float* __restrict__ Y, int nrows, int accumulate)
{
  __shared__ float xs[6*ISZ];
  for (int idx=threadIdx.x; idx<6*ISZ; idx+=1024) xs[idx]=X[idx];
  __syncthreads();
  const int wv = threadIdx.x>>6, ln = threadIdx.x&63;
  const int row = blockIdx.x*16 + wv;
  if (row < nrows){
    const float* wr = W + (size_t)row*ldw;
    float a[6]={0,0,0,0,0,0};
    #pragma unroll 4
    for (int k=ln*4; k<ISZ; k+=256){
      float4 w4 = *(const float4*)(wr + k);
      #pragma unroll
      for (int d=0; d<6; d++){
        float4 x4 = *(const float4*)(xs + d*ISZ + k);
        a[d] += w4.x*x4.x + w4.y*x4.y + w4.z*x4.z + w4.w*x4.w;
      }
    }
    #pragma unroll
    for (int d=0;d<6;d++){
      float v = a[d];
      #pragma unroll
      for (int o=32;o>0;o>>=1) v += __shfl_down(v,o);
      if (ln==0){
        float r = v + (bias? bias[row] : 0.f);
        if (accumulate) Y[d*ISZ+row] += r;
        else            Y[d*ISZ+row]  = r;
      }
    }
  }
}

// ---------------------------------------------------------------------------
// S1: per depth: predvec stats -> perp_pred; softmax(z) -> new_inp; gate
// ---------------------------------------------------------------------------
__global__ __launch_bounds__(1024) void k_s1(
    const float* __restrict__ yff, const float* __restrict__ zz,
    const float* __restrict__ Ivec, const float* __restrict__ Hvec,
    const float* __restrict__ gate_w, const float* __restrict__ gate_b,
    float* __restrict__ newinp, float* __restrict__ scal)
{
  __shared__ float sm[17];
  const int d = blockIdx.x, tid = threadIdx.x;
  const float* y  = yff + d*ISZ;
  const float* z  = zz  + d*ISZ;
  const float* iv = Ivec + d*ISZ;
  const float* hv = Hvec + d*ISZ;

  float m=-FLT_MAX;
  for (int cx=tid;cx<ISZ;cx+=1024) m=fmaxf(m,y[cx]);
  m = blockReduceMax(m,sm);
  float se=0.f;
  for (int cx=tid;cx<ISZ;cx+=1024) se += expf(y[cx]-m);
  se = blockReduceSum(se,sm);
  float lse = m + logf(se);

  float sP=0.f,sQ=0.f,sI=0.f,sH=0.f;
  for (int cx=tid;cx<ISZ;cx+=1024){
    sP += (y[cx]-lse)+EPSF;
    float ivv=iv[cx];
    sQ += ivv+EPSF; sI += ivv; sH += hv[cx];
  }
  sP=blockReduceSum(sP,sm); sQ=blockReduceSum(sQ,sm);
  sI=blockReduceSum(sI,sm); sH=blockReduceSum(sH,sm);

  float kk=0.f;
  for (int cx=tid;cx<ISZ;cx+=1024){
    float ph = ((y[cx]-lse)+EPSF)/sP;
    float qh = (iv[cx]+EPSF)/sQ;
    kk += ph*(logf(ph)-logf(qh));
  }
  kk = blockReduceSum(kk,sm);

  float m2=-FLT_MAX;
  for (int cx=tid;cx<ISZ;cx+=1024) m2=fmaxf(m2,z[cx]);
  m2=blockReduceMax(m2,sm);
  float se2=0.f;
  for (int cx=tid;cx<ISZ;cx+=1024) se2 += expf(z[cx]-m2);
  se2=blockReduceSum(se2,sm);
  float inv2=1.f/se2;
  for (int cx=tid;cx<ISZ;cx+=1024) newinp[d*ISZ+cx] = expf(z[cx]-m2)*inv2;

  if (tid==0){
    float pp=kk;
    float a0=gate_w[0]*pp+gate_b[0];
    float a1=gate_w[1]*pp+gate_b[1];
    float mg=fmaxf(a0,a1);
    float e0=expf(a0-mg), e1=expf(a1-mg);
    float g1=e1/(e0+e1);
    if (sH==0.f) g1=0.f;
    else if (sI==0.f) g1=1.f;
    scal[d]=pp; scal[6+d]=g1;
  }
}

// kld(softmax(logits), qvec) under the reference's +EPS renormalization
__device__ float kld_softmax_vs(const float* __restrict__ lg,
                                const float* __restrict__ qv, float* sm)
{
  const int tid=threadIdx.x;
  float m=-FLT_MAX;
  for (int cx=tid;cx<ISZ;cx+=1024) m=fmaxf(m,lg[cx]);
  m=blockReduceMax(m,sm);
  float se=0.f;
  for (int cx=tid;cx<ISZ;cx+=1024) se+=expf(lg[cx]-m);
  se=blockReduceSum(se,sm);
  float inv=1.f/se;
  float sp=0.f,sq=0.f;
  for (int cx=tid;cx<ISZ;cx+=1024){ sp += expf(lg[cx]-m)*inv + EPSF; sq += qv[cx]+EPSF; }
  sp=blockReduceSum(sp,sm); sq=blockReduceSum(sq,sm);
  float kk=0.f;
  for (int cx=tid;cx<ISZ;cx+=1024){
    float ph=(expf(lg[cx]-m)*inv+EPSF)/sp;
    float qh=(qv[cx]+EPSF)/sq;
    kk += ph*(logf(ph)-logf(qh));
  }
  return blockReduceSum(kk,sm);
}

__global__ __launch_bounds__(1024) void k_s2(
    const float* __restrict__ yh, const float* __restrict__ yi,
    const float* __restrict__ Ivec, const float* __restrict__ Hvec,
    float* __restrict__ scal)
{
  __shared__ float sm[17];
  const int d=blockIdx.x;
  float kh = kld_softmax_vs(yh+d*ISZ, Hvec+d*ISZ, sm);
  float ki = kld_softmax_vs(yi+d*ISZ, Ivec+d*ISZ, sm);
  if (threadIdx.x==0) scal[12+d] = scal[d] + ki*0.5f + kh*0.5f;
}

// wldl chain + resperp
__global__ void k_s3(float* __restrict__ ws, float* __restrict__ out){
  if (threadIdx.x==0 && blockIdx.x==0){
    const float* gate1 = ws + O_SCAL + 6;
    const float* perp  = ws + O_SCAL + 12;
    const float* avail = ws + O_AVAIL;
    float wl[ND];
    wl[0] = gate1[0];
    for (int i=1;i<ND;i++) wl[i] = (1.f - wl[i-1]) * gate1[i] * avail[i];
    float s=0.f; for (int i=0;i<ND;i++) s += wl[i];
    float rp=0.f;
    for (int i=0;i<ND;i++){ float wn = wl[i]/s; ws[O_SCAL+18+i]=wn; rp += wn*perp[i]; }
    out[0]=rp;
  }
}

// combine diag + rank-1 coeffs + pointers; write new_sp / new_ip
__global__ __launch_bounds__(1024) void k_combine(float* __restrict__ ws,
                                                  float* __restrict__ out){
  __shared__ float sm[17];
  const int tid = threadIdx.x;
  float w[ND];
  #pragma unroll
  for (int d=0;d<ND;d++) w[d] = ws[O_SCAL+18+d];
  const float* Dfin = ws+O_DFIN; const float* cnew = ws+O_CNEW;
  const float* cfin = ws+O_CFIN; const float* sptr = ws+O_SPTR;
  float snl[2]; float mysum=0.f;
  for (int jj=0;jj<2;jj++){
    int j = tid + jj*1024;
    float mw=0.f, sn=0.f;
    float ce[10];
    #pragma unroll
    for (int d=0;d<ND;d++){
      mw += w[d]*Dfin[d*HH+j];
      sn += w[d]*sptr[d*HH+j];
      ce[d] = w[d]*cnew[d*HH+j];
    }
    #pragma unroll
    for (int t=0;t<4;t++){
      float a=0.f;
      for (int d=t+2;d<ND;d++) a += w[d]*cfin[(d*4+t)*HH+j];
      ce[6+t]=a;
    }
    ws[O_MW+j]=mw;
    #pragma unroll
    for (int v=0;v<10;v++) ws[O_CEFF + j*10 + v] = ce[v];
    snl[jj]=sn; mysum+=sn;
  }
  float ssum = blockReduceSum(mysum, sm);
  for (int jj=0;jj<2;jj++){
    int j = tid + jj*1024;
    out[1 + (size_t)HH*ISZ + j] = (ssum>0.f)? snl[jj]/ssum : snl[jj];
  }
  if (tid==0){
    const float* iptr = ws+O_IPTR;
    float ipn[WN+1]; float is=0.f;
    for (int k=0;k<=WN;k++){
      float a=0.f;
      for (int d=0;d<ND;d++) a += w[d]*iptr[d*16+k];
      ipn[k]=a; is+=a;
    }
    size_t base = 1 + (size_t)HH*ISZ + HH;
    for (int k=0;k<=WN;k++) out[base+k] = (is>0.f)? ipn[k]/is : ipn[k];
  }
}

// final fused stack pass: out = Mw[j]*stack + sum_v Ceff[j][v]*V[v]
__global__ __launch_bounds__(256) void k_stack_out(
    const float* __restrict__ stk, const float* __restrict__ V,
    const float* __restrict__ Mw, const float* __restrict__ Ceff,
    float* __restrict__ out)
{
  __shared__ float Vt[10*1024];
  const int c0 = blockIdx.x*1024;
  const int j0 = blockIdx.y*8;
  for (int idx=threadIdx.x; idx<10*1024; idx+=256){
    int v=idx>>10, cc=idx&1023;
    Vt[idx] = V[v*ISZ + c0 + cc];
  }
  __syncthreads();
  const int tx4 = threadIdx.x*4;
  for (int r=0;r<8;r++){
    int j=j0+r;
    float mw = Mw[j];
    float ce[10];
    #pragma unroll
    for (int v=0;v<10;v++) ce[v]=Ceff[j*10+v];
    float4 sv = *(const float4*)(stk + (size_t)j*ISZ + c0 + tx4);
    float o0 = mw*sv.x, o1 = mw*sv.y, o2 = mw*sv.z, o3 = mw*sv.w;
    #pragma unroll
    for (int v=0;v<10;v++){
      const float* vr = Vt + v*1024 + tx4;
      float cv=ce[v];
      o0 += cv*vr[0]; o1 += cv*vr[1]; o2 += cv*vr[2]; o3 += cv*vr[3];
    }
    float* op = out + 1 + (size_t)j*ISZ + c0 + tx4;  // +1 breaks 16B align -> scalar stores
    op[0]=o0; op[1]=o1; op[2]=o2; op[3]=o3;
  }
}

extern "C" void kernel_launch(void* const* d_in, const int* in_sizes, int n_in,
                              void* d_out, int out_size, void* d_ws, size_t ws_size,
                              hipStream_t stream)
{
  (void)in_sizes; (void)n_in; (void)out_size; (void)ws_size;
  const float* input   = (const float*)d_in[0];
  const float* stack   = (const float*)d_in[1];
  const float* sp0     = (const float*)d_in[2];
  const float* ip0     = (const float*)d_in[3];
  const float* ff_w    = (const float*)d_in[4];
  const float* ff_b    = (const float*)d_in[5];
  const float* gate_w  = (const float*)d_in[6];
  const float* gate_b  = (const float*)d_in[7];
  const float* kin_w   = (const float*)d_in[8];
  const float* kin_b   = (const float*)d_in[9];
  const float* kouth_w = (const float*)d_in[10];
  const float* kouth_b = (const float*)d_in[11];
  const float* kouti_w = (const float*)d_in[12];
  const float* kouti_b = (const float*)d_in[13];
  float* out = (float*)d_out;
  float* ws  = (float*)d_ws;

  k_ptr_prep<<<1,64,0,stream>>>(sp0, ip0, ws);
  hipMemsetAsync(ws + O_R, 0, (size_t)7*ISZ*sizeof(float), stream);
  k_rowsum<<<dim3(16,32),256,0,stream>>>(stack, ws+O_WROW, ws+O_R);
  k_gvec<<<(5*ISZ+255)/256,256,0,stream>>>(input, ws+O_GETW, ws+O_G);
  k_build_hv<<<(ND*ISZ+255)/256,256,0,stream>>>(ws+O_R, ws+O_G, ws+O_POPC,
                                                ws+O_HVEC, ws+O_IVEC);
  // kin first-half (invec), ff (hvec), kin second-half (hvec, accumulate)
  k_matvec6<<<256,1024,0,stream>>>(kin_w,      8192, ws+O_IVEC, kin_b,   ws+O_Z,   ISZ, 0);
  k_matvec6<<<256,1024,0,stream>>>(ff_w,       4096, ws+O_HVEC, ff_b,    ws+O_YFF, ISZ, 0);
  k_matvec6<<<256,1024,0,stream>>>(kin_w+4096, 8192, ws+O_HVEC, nullptr, ws+O_Z,   ISZ, 1);
  k_s1<<<ND,1024,0,stream>>>(ws+O_YFF, ws+O_Z, ws+O_IVEC, ws+O_HVEC,
                             gate_w, gate_b, ws+O_NEWINP, ws+O_SCAL);
  k_matvec6<<<256,1024,0,stream>>>(kouth_w, 4096, ws+O_NEWINP, kouth_b, ws+O_YH, ISZ, 0);
  k_matvec6<<<256,1024,0,stream>>>(kouti_w, 4096, ws+O_NEWINP, kouti_b, ws+O_YI, ISZ, 0);
  k_s2<<<ND,1024,0,stream>>>(ws+O_YH, ws+O_YI, ws+O_IVEC, ws+O_HVEC, ws+O_SCAL);
  k_s3<<<1,64,0,stream>>>(ws, out);
  k_combine<<<1,1024,0,stream>>>(ws, out);
  k_stack_out<<<dim3(4,256),256,0,stream>>>(stack, ws+O_NEWINP, ws+O_MW, ws+O_CEFF, out);
}

// Round 2
// 209.495 us; speedup vs baseline: 1.8412x; 1.8412x over previous
//
#include <hip/hip_runtime.h>
#include <cfloat>
#include <cmath>

#define HH   2048
#define ISZ  4096
#define WN   10
#define ND   6
#define EPSF 1e-9f

// ---- workspace layout (float offsets), total ~1.39 MB ----
#define O_WROW   0          // 7*2048 row-weight vectors for stack rowsums
#define O_GETW   14336      // 5*16  get weights (ip[0..9] at step t)
#define O_POPC   14464      // 6*4   pop correction coefficients
#define O_AVAIL  14496      // 6
#define O_SCAL   14528      // [0:6] perp_pred [6:12] gate1 [12:18] perp [18:24] w
#define O_IPTR   14592      // 6*16  ip trajectory
#define O_DFIN   14720      // 6*2048 final diag per depth
#define O_CNEW   27008      // 6*2048 new_inp push coeff per depth
#define O_CFIN   39296      // 6*4*2048 g-term coeffs per depth
#define O_SPTR   88448      // 6*2048 final stack pointers
#define O_MW     100736     // 2048 combined diag
#define O_CEFF   104832     // 2048*10 combined rank-1 coeffs
#define O_R      125312     // 7*4096 stack rowsums
#define O_NEWINP 153984     // 6*4096 (V rows 0..5)
#define O_G      178560     // 5*4096 (V rows 6..9; MUST be O_NEWINP+6*ISZ)
#define O_HVEC   199040     // 6*4096
#define O_IVEC   223616     // 6*4096
#define O_YFF    248192     // 6*4096
#define O_Z      272768     // 6*4096
#define O_YH     297344     // 6*4096
#define O_YI     321920     // 6*4096

__device__ __forceinline__ float blockReduceSum(float v, float* sm){
  int ln = threadIdx.x & 63, w = threadIdx.x >> 6;
  #pragma unroll
  for (int o=32;o>0;o>>=1) v += __shfl_down(v,o);
  if (ln==0) sm[w]=v;
  __syncthreads();
  if (threadIdx.x==0){
    float r=0.f; int nw=(int)(blockDim.x>>6);
    for (int i=0;i<nw;i++) r+=sm[i];
    sm[16]=r;
  }
  __syncthreads();
  float r = sm[16];
  __syncthreads();
  return r;
}

__device__ __forceinline__ float blockReduceMax(float v, float* sm){
  int ln = threadIdx.x & 63, w = threadIdx.x >> 6;
  #pragma unroll
  for (int o=32;o>0;o>>=1) v = fmaxf(v,__shfl_down(v,o));
  if (ln==0) sm[w]=v;
  __syncthreads();
  if (threadIdx.x==0){
    float r=-FLT_MAX; int nw=(int)(blockDim.x>>6);
    for (int i=0;i<nw;i++) r=fmaxf(r,sm[i]);
    sm[16]=r;
  }
  __syncthreads();
  float r = sm[16];
  __syncthreads();
  return r;
}

// ---------------------------------------------------------------------------
// K1: pointer algebra (data-independent). 6 blocks (one per depth) x 1024 thr.
// Block d computes depth d's Wrow row(s), popc, Dfin, cfin, cnew, sptr.
// Block 0 additionally: ip trajectory (serial, tiny) + Wrow rows 0,1.
// ---------------------------------------------------------------------------
__global__ __launch_bounds__(1024) void k_ptr_prep(
    const float* __restrict__ sp0g, const float* __restrict__ ip0g,
    float* __restrict__ ws)
{
  __shared__ float sp[HH], q[HH], D[HH];
  __shared__ float c[4][HH];
  __shared__ float red[17];
  const int d   = blockIdx.x;
  const int tid = threadIdx.x;

  float* Wrow = ws + O_WROW;
  float* getW = ws + O_GETW;
  float* popc = ws + O_POPC;
  float* Dfin = ws + O_DFIN;
  float* cnew = ws + O_CNEW;
  float* cfin = ws + O_CFIN;
  float* sptr = ws + O_SPTR;
  float* iptr = ws + O_IPTR;
  float* avail= ws + O_AVAIL;

  if (d==0 && tid==0){
    // input-pointer trajectory (11 wide) — trivial serial work
    float ip[WN+1], nip[WN+1];
    for (int k=0;k<=WN;k++) ip[k]=ip0g[k];
    for (int k=0;k<=WN;k++) iptr[k]=ip[k];
    avail[0] = 1.f - ip[WN];
    for (int t=0;t<5;t++){
      for (int k=0;k<WN;k++) getW[t*16+k]=ip[k];
      nip[0]=0.f;
      for (int k=1;k<=WN;k++) nip[k]=ip[k-1];
      nip[WN] += ip[WN];
      for (int k=0;k<=WN;k++) ip[k]=nip[k];
      for (int k=0;k<=WN;k++) iptr[(t+1)*16+k]=ip[k];
      avail[t+1] = 1.f - ip[WN];
    }
  }

  // load initial stack pointer
  #pragma unroll
  for (int jj=0;jj<2;jj++){ int j=tid+jj*1024; sp[j]=sp0g[j]; D[j]=1.f; }
  __syncthreads();

  if (d==0){
    // ---------- depth 0: pop, pop, push ----------
    // pop 1
    #pragma unroll
    for (int jj=0;jj<2;jj++){ int j=tid+jj*1024; q[j]=(j<HH-1)? sp[j+1]:0.f; }
    float ls=0.f;
    #pragma unroll
    for (int jj=0;jj<2;jj++) ls += q[tid+jj*1024];
    float s = blockReduceSum(ls, red);           // syncs: q final, sp reads done
    float sc = (s>0.f)? 1.f/s : 1.f;
    #pragma unroll
    for (int jj=0;jj<2;jj++){
      int j=tid+jj*1024;
      float qq=q[j];
      Wrow[j] = qq*sc;
      D[j] = 1.f - qq;
      sp[j] = qq + ((j==0)? sp[0] : 0.f);        // only thread owning j==0 touches sp[0]
    }
    __syncthreads();
    // pop 2
    #pragma unroll
    for (int jj=0;jj<2;jj++){ int j=tid+jj*1024; q[j]=(j<HH-1)? sp[j+1]:0.f; }
    ls=0.f;
    #pragma unroll
    for (int jj=0;jj<2;jj++) ls += q[tid+jj*1024];
    s = blockReduceSum(ls, red);
    sc = (s>0.f)? 1.f/s : 1.f;
    #pragma unroll
    for (int jj=0;jj<2;jj++){
      int j=tid+jj*1024;
      float qq=q[j];
      Wrow[HH+j] = qq*sc*D[j];
      D[j] *= (1.f-qq);
      sp[j] = qq + ((j==0)? sp[0] : 0.f);
    }
    __syncthreads();
    // final push of new_inp_0
    #pragma unroll
    for (int jj=0;jj<2;jj++){
      int j=tid+jj*1024;
      float p=sp[j];
      Dfin[j] = D[j]*(1.f-p);
      cnew[j] = p;
      sptr[j] = (j==0)? 0.f : sp[j-1];
    }
  } else {
    // ---------- depth d (1..5): (d-1) get-pushes, pop, push ----------
    const int nterms = d-1;
    for (int t=0;t<nterms;t++){
      #pragma unroll
      for (int jj=0;jj<2;jj++){
        int j=tid+jj*1024;
        float p=sp[j], f=1.f-p;
        D[j]*=f;
        for (int u=0;u<t;u++) c[u][j]*=f;
        c[t][j]=p;
      }
      __syncthreads();
      float sv[2];
      #pragma unroll
      for (int jj=0;jj<2;jj++){ int j=tid+jj*1024; sv[jj]=(j==0)?0.f:sp[j-1]; }
      __syncthreads();
      #pragma unroll
      for (int jj=0;jj<2;jj++){ int j=tid+jj*1024; sp[j]=sv[jj]; }
      __syncthreads();
    }
    // pop
    #pragma unroll
    for (int jj=0;jj<2;jj++){ int j=tid+jj*1024; q[j]=(j<HH-1)? sp[j+1]:0.f; }
    float ls=0.f;
    #pragma unroll
    for (int jj=0;jj<2;jj++) ls += q[tid+jj*1024];
    float s = blockReduceSum(ls, red);
    float sc = (s>0.f)? 1.f/s : 1.f;
    for (int t=0;t<nterms;t++){
      float pc=0.f;
      #pragma unroll
      for (int jj=0;jj<2;jj++){ int j=tid+jj*1024; pc += q[j]*sc*c[t][j]; }
      pc = blockReduceSum(pc, red);
      if (tid==0) popc[d*4+t]=pc;
    }
    #pragma unroll
    for (int jj=0;jj<2;jj++){
      int j=tid+jj*1024;
      float qq=q[j];
      Wrow[(1+d)*HH+j] = qq*sc*D[j];
      float f = 1.f-qq;
      D[j] *= f;
      for (int t=0;t<nterms;t++) c[t][j] *= f;
      sp[j] = qq + ((j==0)? sp[0] : 0.f);
    }
    __syncthreads();
    // final push of new_inp_d
    #pragma unroll
    for (int jj=0;jj<2;jj++){
      int j=tid+jj*1024;
      float p=sp[j], f=1.f-p;
      Dfin[d*HH+j] = D[j]*f;
      for (int t=0;t<nterms;t++) cfin[(d*4+t)*HH+j] = c[t][j]*f;
      cnew[d*HH+j] = p;
      sptr[d*HH+j] = (j==0)? 0.f : sp[j-1];
    }
  }
}

// ---------------------------------------------------------------------------
// K2: R[k][col] = sum_j Wrow[k][j] * stack[j][col]  (7 weighted rowsums)
// ---------------------------------------------------------------------------
__global__ __launch_bounds__(256) void k_rowsum(
    const float* __restrict__ stk, const float* __restrict__ wrow,
    float* __restrict__ R)
{
  __shared__ float wsh[7][64];
  const int col = blockIdx.x*256 + threadIdx.x;
  const int r0  = blockIdx.y*64;
  for (int idx=threadIdx.x; idx<7*64; idx+=256){
    int k=idx>>6, r=idx&63;
    wsh[k][r]=wrow[k*HH + r0 + r];
  }
  __syncthreads();
  float a0=0,a1=0,a2=0,a3=0,a4=0,a5=0,a6=0;
  const float* sp = stk + (size_t)r0*ISZ + col;
  #pragma unroll 4
  for (int r=0;r<64;r++){
    float v = sp[(size_t)r*ISZ];
    a0+=wsh[0][r]*v; a1+=wsh[1][r]*v; a2+=wsh[2][r]*v; a3+=wsh[3][r]*v;
    a4+=wsh[4][r]*v; a5+=wsh[5][r]*v; a6+=wsh[6][r]*v;
  }
  atomicAdd(&R[0*ISZ+col],a0); atomicAdd(&R[1*ISZ+col],a1);
  atomicAdd(&R[2*ISZ+col],a2); atomicAdd(&R[3*ISZ+col],a3);
  atomicAdd(&R[4*ISZ+col],a4); atomicAdd(&R[5*ISZ+col],a5);
  atomicAdd(&R[6*ISZ+col],a6);
}

// g_t = getW[t][0..9] @ input  (5 vectors)
__global__ void k_gvec(const float* __restrict__ input,
                       const float* __restrict__ getW, float* __restrict__ g)
{
  int idx = blockIdx.x*256+threadIdx.x;
  if (idx >= 5*ISZ) return;
  int t = idx / ISZ, cx = idx % ISZ;
  float acc=0.f;
  #pragma unroll
  for (int k=0;k<WN;k++) acc += getW[t*16+k]*input[k*ISZ + cx];
  g[idx] = acc;
}

// Hvec/Ivec assembly
__global__ void k_build_hv(const float* __restrict__ R, const float* __restrict__ g,
                           const float* __restrict__ popc,
                           float* __restrict__ Hvec, float* __restrict__ Ivec)
{
  int idx = blockIdx.x*256+threadIdx.x;
  if (idx >= ND*ISZ) return;
  int d = idx/ISZ, cx = idx%ISZ;
  if (d==0){ Ivec[idx]=R[cx]; Hvec[idx]=R[ISZ+cx]; }
  else {
    Ivec[idx]=g[(d-1)*ISZ+cx];
    float h = R[(1+d)*ISZ+cx];
    for (int t=0;t<=d-2;t++) h += popc[d*4+t]*g[t*ISZ+cx];
    Hvec[idx]=h;
  }
}

// ---------------------------------------------------------------------------
// Batched (6-vector) matvec: Y[d][row] (+)= sum_k W[row][k]*X[d][k] + bias
// One row per wave, X staged in LDS (96 KB).
// ---------------------------------------------------------------------------
__global__ __launch_bounds__(1024) void k_matvec6(
    const float* __restrict__ W, int ldw,
    const float* __restrict__ X, const float* __restrict__ bias,
    float* __restrict__ Y, int nrows, int accumulate)
{
  __shared__ float xs[6*ISZ];
  for (int idx=threadIdx.x; idx<6*ISZ; idx+=1024) xs[idx]=X[idx];
  __syncthreads();
  const int wv = threadIdx.x>>6, ln = threadIdx.x&63;
  const int row = blockIdx.x*16 + wv;
  if (row < nrows){
    const float* wr = W + (size_t)row*ldw;
    float a[6]={0,0,0,0,0,0};
    #pragma unroll 4
    for (int k=ln*4; k<ISZ; k+=256){
      float4 w4 = *(const float4*)(wr + k);
      #pragma unroll
      for (int d=0; d<6; d++){
        float4 x4 = *(const float4*)(xs + d*ISZ + k);
        a[d] += w4.x*x4.x + w4.y*x4.y + w4.z*x4.z + w4.w*x4.w;
      }
    }
    #pragma unroll
    for (int d=0;d<6;d++){
      float v = a[d];
      #pragma unroll
      for (int o=32;o>0;o>>=1) v += __shfl_down(v,o);
      if (ln==0){
        float r = v + (bias? bias[row] : 0.f);
        if (accumulate) Y[d*ISZ+row] += r;
        else            Y[d*ISZ+row]  = r;
      }
    }
  }
}

// ---------------------------------------------------------------------------
// S1: per depth: predvec stats -> perp_pred; softmax(z) -> new_inp; gate
// ---------------------------------------------------------------------------
__global__ __launch_bounds__(1024) void k_s1(
    const float* __restrict__ yff, const float* __restrict__ zz,
    const float* __restrict__ Ivec, const float* __restrict__ Hvec,
    const float* __restrict__ gate_w, const float* __restrict__ gate_b,
    float* __restrict__ newinp, float* __restrict__ scal)
{
  __shared__ float sm[17];
  const int d = blockIdx.x, tid = threadIdx.x;
  const float* y  = yff + d*ISZ;
  const float* z  = zz  + d*ISZ;
  const float* iv = Ivec + d*ISZ;
  const float* hv = Hvec + d*ISZ;

  float m=-FLT_MAX;
  for (int cx=tid;cx<ISZ;cx+=1024) m=fmaxf(m,y[cx]);
  m = blockReduceMax(m,sm);
  float se=0.f;
  for (int cx=tid;cx<ISZ;cx+=1024) se += expf(y[cx]-m);
  se = blockReduceSum(se,sm);
  float lse = m + logf(se);

  float sP=0.f,sQ=0.f,sI=0.f,sH=0.f;
  for (int cx=tid;cx<ISZ;cx+=1024){
    sP += (y[cx]-lse)+EPSF;
    float ivv=iv[cx];
    sQ += ivv+EPSF; sI += ivv; sH += hv[cx];
  }
  sP=blockReduceSum(sP,sm); sQ=blockReduceSum(sQ,sm);
  sI=blockReduceSum(sI,sm); sH=blockReduceSum(sH,sm);

  float kk=0.f;
  for (int cx=tid;cx<ISZ;cx+=1024){
    float ph = ((y[cx]-lse)+EPSF)/sP;
    float qh = (iv[cx]+EPSF)/sQ;
    kk += ph*(logf(ph)-logf(qh));
  }
  kk = blockReduceSum(kk,sm);

  float m2=-FLT_MAX;
  for (int cx=tid;cx<ISZ;cx+=1024) m2=fmaxf(m2,z[cx]);
  m2=blockReduceMax(m2,sm);
  float se2=0.f;
  for (int cx=tid;cx<ISZ;cx+=1024) se2 += expf(z[cx]-m2);
  se2=blockReduceSum(se2,sm);
  float inv2=1.f/se2;
  for (int cx=tid;cx<ISZ;cx+=1024) newinp[d*ISZ+cx] = expf(z[cx]-m2)*inv2;

  if (tid==0){
    float pp=kk;
    float a0=gate_w[0]*pp+gate_b[0];
    float a1=gate_w[1]*pp+gate_b[1];
    float mg=fmaxf(a0,a1);
    float e0=expf(a0-mg), e1=expf(a1-mg);
    float g1=e1/(e0+e1);
    if (sH==0.f) g1=0.f;
    else if (sI==0.f) g1=1.f;
    scal[d]=pp; scal[6+d]=g1;
  }
}

// kld(softmax(logits), qvec) under the reference's +EPS renormalization
__device__ float kld_softmax_vs(const float* __restrict__ lg,
                                const float* __restrict__ qv, float* sm)
{
  const int tid=threadIdx.x;
  float m=-FLT_MAX;
  for (int cx=tid;cx<ISZ;cx+=1024) m=fmaxf(m,lg[cx]);
  m=blockReduceMax(m,sm);
  float se=0.f;
  for (int cx=tid;cx<ISZ;cx+=1024) se+=expf(lg[cx]-m);
  se=blockReduceSum(se,sm);
  float inv=1.f/se;
  float sp=0.f,sq=0.f;
  for (int cx=tid;cx<ISZ;cx+=1024){ sp += expf(lg[cx]-m)*inv + EPSF; sq += qv[cx]+EPSF; }
  sp=blockReduceSum(sp,sm); sq=blockReduceSum(sq,sm);
  float kk=0.f;
  for (int cx=tid;cx<ISZ;cx+=1024){
    float ph=(expf(lg[cx]-m)*inv+EPSF)/sp;
    float qh=(qv[cx]+EPSF)/sq;
    kk += ph*(logf(ph)-logf(qh));
  }
  return blockReduceSum(kk,sm);
}

__global__ __launch_bounds__(1024) void k_s2(
    const float* __restrict__ yh, const float* __restrict__ yi,
    const float* __restrict__ Ivec, const float* __restrict__ Hvec,
    float* __restrict__ scal)
{
  __shared__ float sm[17];
  const int d=blockIdx.x;
  float kh = kld_softmax_vs(yh+d*ISZ, Hvec+d*ISZ, sm);
  float ki = kld_softmax_vs(yi+d*ISZ, Ivec+d*ISZ, sm);
  if (threadIdx.x==0) scal[12+d] = scal[d] + ki*0.5f + kh*0.5f;
}

// wldl chain + resperp
__global__ void k_s3(float* __restrict__ ws, float* __restrict__ out){
  if (threadIdx.x==0 && blockIdx.x==0){
    const float* gate1 = ws + O_SCAL + 6;
    const float* perp  = ws + O_SCAL + 12;
    const float* avail = ws + O_AVAIL;
    float wl[ND];
    wl[0] = gate1[0];
    for (int i=1;i<ND;i++) wl[i] = (1.f - wl[i-1]) * gate1[i] * avail[i];
    float s=0.f; for (int i=0;i<ND;i++) s += wl[i];
    float rp=0.f;
    for (int i=0;i<ND;i++){ float wn = wl[i]/s; ws[O_SCAL+18+i]=wn; rp += wn*perp[i]; }
    out[0]=rp;
  }
}

// combine diag + rank-1 coeffs + pointers; write new_sp / new_ip
__global__ __launch_bounds__(1024) void k_combine(float* __restrict__ ws,
                                                  float* __restrict__ out){
  __shared__ float sm[17];
  const int tid = threadIdx.x;
  float w[ND];
  #pragma unroll
  for (int d=0;d<ND;d++) w[d] = ws[O_SCAL+18+d];
  const float* Dfin = ws+O_DFIN; const float* cnew = ws+O_CNEW;
  const float* cfin = ws+O_CFIN; const float* sptr = ws+O_SPTR;
  float snl[2]; float mysum=0.f;
  for (int jj=0;jj<2;jj++){
    int j = tid + jj*1024;
    float mw=0.f, sn=0.f;
    float ce[10];
    #pragma unroll
    for (int d=0;d<ND;d++){
      mw += w[d]*Dfin[d*HH+j];
      sn += w[d]*sptr[d*HH+j];
      ce[d] = w[d]*cnew[d*HH+j];
    }
    #pragma unroll
    for (int t=0;t<4;t++){
      float a=0.f;
      for (int d=t+2;d<ND;d++) a += w[d]*cfin[(d*4+t)*HH+j];
      ce[6+t]=a;
    }
    ws[O_MW+j]=mw;
    #pragma unroll
    for (int v=0;v<10;v++) ws[O_CEFF + j*10 + v] = ce[v];
    snl[jj]=sn; mysum+=sn;
  }
  float ssum = blockReduceSum(mysum, sm);
  for (int jj=0;jj<2;jj++){
    int j = tid + jj*1024;
    out[1 + (size_t)HH*ISZ + j] = (ssum>0.f)? snl[jj]/ssum : snl[jj];
  }
  if (tid==0){
    const float* iptr = ws+O_IPTR;
    float ipn[WN+1]; float is=0.f;
    for (int k=0;k<=WN;k++){
      float a=0.f;
      for (int d=0;d<ND;d++) a += w[d]*iptr[d*16+k];
      ipn[k]=a; is+=a;
    }
    size_t base = 1 + (size_t)HH*ISZ + HH;
    for (int k=0;k<=WN;k++) out[base+k] = (is>0.f)? ipn[k]/is : ipn[k];
  }
}

// final fused stack pass: out = Mw[j]*stack + sum_v Ceff[j][v]*V[v]
__global__ __launch_bounds__(256) void k_stack_out(
    const float* __restrict__ stk, const float* __restrict__ V,
    const float* __restrict__ Mw, const float* __restrict__ Ceff,
    float* __restrict__ out)
{
  __shared__ float Vt[10*1024];
  const int c0 = blockIdx.x*1024;
  const int j0 = blockIdx.y*8;
  for (int idx=threadIdx.x; idx<10*1024; idx+=256){
    int v=idx>>10, cc=idx&1023;
    Vt[idx] = V[v*ISZ + c0 + cc];
  }
  __syncthreads();
  const int tx4 = threadIdx.x*4;
  for (int r=0;r<8;r++){
    int j=j0+r;
    float mw = Mw[j];
    float ce[10];
    #pragma unroll
    for (int v=0;v<10;v++) ce[v]=Ceff[j*10+v];
    float4 sv = *(const float4*)(stk + (size_t)j*ISZ + c0 + tx4);
    float o0 = mw*sv.x, o1 = mw*sv.y, o2 = mw*sv.z, o3 = mw*sv.w;
    #pragma unroll
    for (int v=0;v<10;v++){
      const float* vr = Vt + v*1024 + tx4;
      float cv=ce[v];
      o0 += cv*vr[0]; o1 += cv*vr[1]; o2 += cv*vr[2]; o3 += cv*vr[3];
    }
    float* op = out + 1 + (size_t)j*ISZ + c0 + tx4;  // +1 breaks 16B align -> scalar stores
    op[0]=o0; op[1]=o1; op[2]=o2; op[3]=o3;
  }
}

extern "C" void kernel_launch(void* const* d_in, const int* in_sizes, int n_in,
                              void* d_out, int out_size, void* d_ws, size_t ws_size,
                              hipStream_t stream)
{
  (void)in_sizes; (void)n_in; (void)out_size; (void)ws_size;
  const float* input   = (const float*)d_in[0];
  const float* stack   = (const float*)d_in[1];
  const float* sp0     = (const float*)d_in[2];
  const float* ip0     = (const float*)d_in[3];
  const float* ff_w    = (const float*)d_in[4];
  const float* ff_b    = (const float*)d_in[5];
  const float* gate_w  = (const float*)d_in[6];
  const float* gate_b  = (const float*)d_in[7];
  const float* kin_w   = (const float*)d_in[8];
  const float* kin_b   = (const float*)d_in[9];
  const float* kouth_w = (const float*)d_in[10];
  const float* kouth_b = (const float*)d_in[11];
  const float* kouti_w = (const float*)d_in[12];
  const float* kouti_b = (const float*)d_in[13];
  float* out = (float*)d_out;
  float* ws  = (float*)d_ws;

  k_ptr_prep<<<ND,1024,0,stream>>>(sp0, ip0, ws);
  hipMemsetAsync(ws + O_R, 0, (size_t)7*ISZ*sizeof(float), stream);
  k_rowsum<<<dim3(16,32),256,0,stream>>>(stack, ws+O_WROW, ws+O_R);
  k_gvec<<<(5*ISZ+255)/256,256,0,stream>>>(input, ws+O_GETW, ws+O_G);
  k_build_hv<<<(ND*ISZ+255)/256,256,0,stream>>>(ws+O_R, ws+O_G, ws+O_POPC,
                                                ws+O_HVEC, ws+O_IVEC);
  // kin first-half (invec), ff (hvec), kin second-half (hvec, accumulate)
  k_matvec6<<<256,1024,0,stream>>>(kin_w,      8192, ws+O_IVEC, kin_b,   ws+O_Z,   ISZ, 0);
  k_matvec6<<<256,1024,0,stream>>>(ff_w,       4096, ws+O_HVEC, ff_b,    ws+O_YFF, ISZ, 0);
  k_matvec6<<<256,1024,0,stream>>>(kin_w+4096, 8192, ws+O_HVEC, nullptr, ws+O_Z,   ISZ, 1);
  k_s1<<<ND,1024,0,stream>>>(ws+O_YFF, ws+O_Z, ws+O_IVEC, ws+O_HVEC,
                             gate_w, gate_b, ws+O_NEWINP, ws+O_SCAL);
  k_matvec6<<<256,1024,0,stream>>>(kouth_w, 4096, ws+O_NEWINP, kouth_b, ws+O_YH, ISZ, 0);
  k_matvec6<<<256,1024,0,stream>>>(kouti_w, 4096, ws+O_NEWINP, kouti_b, ws+O_YI, ISZ, 0);
  k_s2<<<ND,1024,0,stream>>>(ws+O_YH, ws+O_YI, ws+O_IVEC, ws+O_HVEC, ws+O_SCAL);
  k_s3<<<1,64,0,stream>>>(ws, out);
  k_combine<<<1,1024,0,stream>>>(ws, out);
  k_stack_out<<<dim3(4,256),256,0,stream>>>(stack, ws+O_NEWINP, ws+O_MW, ws+O_CEFF, out);
}

// Round 3
// 204.272 us; speedup vs baseline: 1.8883x; 1.0256x over previous
//
#include <hip/hip_runtime.h>
#include <cfloat>
#include <cmath>

#define HH   2048
#define ISZ  4096
#define WN   10
#define ND   6
#define EPSF 1e-9f

// ---- workspace layout (float offsets), ~5 MB ----
#define O_WROW   0          // 7*2048
#define O_GETW   14336      // 5*16
#define O_POPC   14464      // 6*4
#define O_AVAIL  14496      // 6
#define O_SCAL   14528      // [0:6]pp [6:12]gate1 [12:18]perp [24:30]sQi [30:36]sQh
#define O_IPTR   14592      // 6*16
#define O_DFIN   14720      // 6*2048
#define O_CNEW   27008      // 6*2048
#define O_CFIN   39296      // 6*4*2048
#define O_SPTR   88448      // 6*2048
#define O_NEWINP 100736     // 6*4096 (V rows 0..5)
#define O_G      125312     // 5*4096 (V rows 6..9 = g[0..3]; MUST follow O_NEWINP)
#define O_HVEC   145792     // 6*4096
#define O_IVEC   170368     // 6*4096
#define O_YFF    194944     // 6*4096
#define O_Z1     219520     // 6*4096
#define O_Z2     244096     // 6*4096
#define O_YH     268672     // 6*4096
#define O_YI     293248     // 6*4096
#define O_RPART  317824     // 32*7*4096 rowsum partials

__device__ __forceinline__ float blockReduceSum(float v, float* sm){
  int ln = threadIdx.x & 63, w = threadIdx.x >> 6;
  #pragma unroll
  for (int o=32;o>0;o>>=1) v += __shfl_down(v,o);
  if (ln==0) sm[w]=v;
  __syncthreads();
  if (threadIdx.x==0){
    float r=0.f; int nw=(int)(blockDim.x>>6);
    for (int i=0;i<nw;i++) r+=sm[i];
    sm[16]=r;
  }
  __syncthreads();
  float r = sm[16];
  __syncthreads();
  return r;
}

// batched reductions for 1024-thread blocks (16 waves)
template<int N>
__device__ __forceinline__ void bRedSumN(float* v, float* sm){
  int ln=threadIdx.x&63, w=threadIdx.x>>6;
  #pragma unroll
  for (int o=32;o>0;o>>=1){
    #pragma unroll
    for (int i=0;i<N;i++) v[i]+=__shfl_down(v[i],o);
  }
  if (ln==0){ for (int i=0;i<N;i++) sm[w*N+i]=v[i]; }
  __syncthreads();
  if (threadIdx.x==0){
    for (int i=0;i<N;i++){ float r=0.f; for (int q=0;q<16;q++) r+=sm[q*N+i]; sm[16*N+i]=r; }
  }
  __syncthreads();
  for (int i=0;i<N;i++) v[i]=sm[16*N+i];
  __syncthreads();
}

template<int N>
__device__ __forceinline__ void bRedMaxN(float* v, float* sm){
  int ln=threadIdx.x&63, w=threadIdx.x>>6;
  #pragma unroll
  for (int o=32;o>0;o>>=1){
    #pragma unroll
    for (int i=0;i<N;i++) v[i]=fmaxf(v[i],__shfl_down(v[i],o));
  }
  if (ln==0){ for (int i=0;i<N;i++) sm[w*N+i]=v[i]; }
  __syncthreads();
  if (threadIdx.x==0){
    for (int i=0;i<N;i++){ float r=-FLT_MAX; for (int q=0;q<16;q++) r=fmaxf(r,sm[q*N+i]); sm[16*N+i]=r; }
  }
  __syncthreads();
  for (int i=0;i<N;i++) v[i]=sm[16*N+i];
  __syncthreads();
}

// ---------------------------------------------------------------------------
// K1: pointer algebra (data-independent). 6 blocks x 1024 threads.
// ---------------------------------------------------------------------------
__global__ __launch_bounds__(1024) void k_ptr_prep(
    const float* __restrict__ sp0g, const float* __restrict__ ip0g,
    float* __restrict__ ws)
{
  __shared__ float sp[HH], q[HH], D[HH];
  __shared__ float c[4][HH];
  __shared__ float red[17];
  const int d   = blockIdx.x;
  const int tid = threadIdx.x;

  float* Wrow = ws + O_WROW;
  float* getW = ws + O_GETW;
  float* popc = ws + O_POPC;
  float* Dfin = ws + O_DFIN;
  float* cnew = ws + O_CNEW;
  float* cfin = ws + O_CFIN;
  float* sptr = ws + O_SPTR;
  float* iptr = ws + O_IPTR;
  float* avail= ws + O_AVAIL;

  if (d==0 && tid==0){
    float ip[WN+1], nip[WN+1];
    for (int k=0;k<=WN;k++) ip[k]=ip0g[k];
    for (int k=0;k<=WN;k++) iptr[k]=ip[k];
    avail[0] = 1.f - ip[WN];
    for (int t=0;t<5;t++){
      for (int k=0;k<WN;k++) getW[t*16+k]=ip[k];
      nip[0]=0.f;
      for (int k=1;k<=WN;k++) nip[k]=ip[k-1];
      nip[WN] += ip[WN];
      for (int k=0;k<=WN;k++) ip[k]=nip[k];
      for (int k=0;k<=WN;k++) iptr[(t+1)*16+k]=ip[k];
      avail[t+1] = 1.f - ip[WN];
    }
  }

  #pragma unroll
  for (int jj=0;jj<2;jj++){ int j=tid+jj*1024; sp[j]=sp0g[j]; D[j]=1.f; }
  __syncthreads();

  if (d==0){
    // pop 1
    #pragma unroll
    for (int jj=0;jj<2;jj++){ int j=tid+jj*1024; q[j]=(j<HH-1)? sp[j+1]:0.f; }
    float ls=0.f;
    #pragma unroll
    for (int jj=0;jj<2;jj++) ls += q[tid+jj*1024];
    float s = blockReduceSum(ls, red);
    float sc = (s>0.f)? 1.f/s : 1.f;
    #pragma unroll
    for (int jj=0;jj<2;jj++){
      int j=tid+jj*1024;
      float qq=q[j];
      Wrow[j] = qq*sc;
      D[j] = 1.f - qq;
      sp[j] = qq + ((j==0)? sp[0] : 0.f);
    }
    __syncthreads();
    // pop 2
    #pragma unroll
    for (int jj=0;jj<2;jj++){ int j=tid+jj*1024; q[j]=(j<HH-1)? sp[j+1]:0.f; }
    ls=0.f;
    #pragma unroll
    for (int jj=0;jj<2;jj++) ls += q[tid+jj*1024];
    s = blockReduceSum(ls, red);
    sc = (s>0.f)? 1.f/s : 1.f;
    #pragma unroll
    for (int jj=0;jj<2;jj++){
      int j=tid+jj*1024;
      float qq=q[j];
      Wrow[HH+j] = qq*sc*D[j];
      D[j] *= (1.f-qq);
      sp[j] = qq + ((j==0)? sp[0] : 0.f);
    }
    __syncthreads();
    #pragma unroll
    for (int jj=0;jj<2;jj++){
      int j=tid+jj*1024;
      float p=sp[j];
      Dfin[j] = D[j]*(1.f-p);
      cnew[j] = p;
      sptr[j] = (j==0)? 0.f : sp[j-1];
    }
  } else {
    const int nterms = d-1;
    for (int t=0;t<nterms;t++){
      #pragma unroll
      for (int jj=0;jj<2;jj++){
        int j=tid+jj*1024;
        float p=sp[j], f=1.f-p;
        D[j]*=f;
        for (int u=0;u<t;u++) c[u][j]*=f;
        c[t][j]=p;
      }
      __syncthreads();
      float sv[2];
      #pragma unroll
      for (int jj=0;jj<2;jj++){ int j=tid+jj*1024; sv[jj]=(j==0)?0.f:sp[j-1]; }
      __syncthreads();
      #pragma unroll
      for (int jj=0;jj<2;jj++){ int j=tid+jj*1024; sp[j]=sv[jj]; }
      __syncthreads();
    }
    // pop
    #pragma unroll
    for (int jj=0;jj<2;jj++){ int j=tid+jj*1024; q[j]=(j<HH-1)? sp[j+1]:0.f; }
    float ls=0.f;
    #pragma unroll
    for (int jj=0;jj<2;jj++) ls += q[tid+jj*1024];
    float s = blockReduceSum(ls, red);
    float sc = (s>0.f)? 1.f/s : 1.f;
    for (int t=0;t<nterms;t++){
      float pc=0.f;
      #pragma unroll
      for (int jj=0;jj<2;jj++){ int j=tid+jj*1024; pc += q[j]*sc*c[t][j]; }
      pc = blockReduceSum(pc, red);
      if (tid==0) popc[d*4+t]=pc;
    }
    #pragma unroll
    for (int jj=0;jj<2;jj++){
      int j=tid+jj*1024;
      float qq=q[j];
      Wrow[(1+d)*HH+j] = qq*sc*D[j];
      float f = 1.f-qq;
      D[j] *= f;
      for (int t=0;t<nterms;t++) c[t][j] *= f;
      sp[j] = qq + ((j==0)? sp[0] : 0.f);
    }
    __syncthreads();
    #pragma unroll
    for (int jj=0;jj<2;jj++){
      int j=tid+jj*1024;
      float p=sp[j], f=1.f-p;
      Dfin[d*HH+j] = D[j]*f;
      for (int t=0;t<nterms;t++) cfin[(d*4+t)*HH+j] = c[t][j]*f;
      cnew[d*HH+j] = p;
      sptr[d*HH+j] = (j==0)? 0.f : sp[j-1];
    }
  }
}

// ---------------------------------------------------------------------------
// K2: rowsum partials, atomic-free: Rp[y][k][col]
// ---------------------------------------------------------------------------
__global__ __launch_bounds__(256) void k_rowsum(
    const float* __restrict__ stk, const float* __restrict__ wrow,
    float* __restrict__ Rp)
{
  __shared__ float wsh[7][64];
  const int col = blockIdx.x*256 + threadIdx.x;
  const int by  = blockIdx.y;
  const int r0  = by*64;
  for (int idx=threadIdx.x; idx<7*64; idx+=256){
    int k=idx>>6, r=idx&63;
    wsh[k][r]=wrow[k*HH + r0 + r];
  }
  __syncthreads();
  float a0=0,a1=0,a2=0,a3=0,a4=0,a5=0,a6=0;
  const float* sp = stk + (size_t)r0*ISZ + col;
  #pragma unroll 4
  for (int r=0;r<64;r++){
    float v = sp[(size_t)r*ISZ];
    a0+=wsh[0][r]*v; a1+=wsh[1][r]*v; a2+=wsh[2][r]*v; a3+=wsh[3][r]*v;
    a4+=wsh[4][r]*v; a5+=wsh[5][r]*v; a6+=wsh[6][r]*v;
  }
  Rp[(size_t)(by*7+0)*ISZ+col]=a0; Rp[(size_t)(by*7+1)*ISZ+col]=a1;
  Rp[(size_t)(by*7+2)*ISZ+col]=a2; Rp[(size_t)(by*7+3)*ISZ+col]=a3;
  Rp[(size_t)(by*7+4)*ISZ+col]=a4; Rp[(size_t)(by*7+5)*ISZ+col]=a5;
  Rp[(size_t)(by*7+6)*ISZ+col]=a6;
}

// ---------------------------------------------------------------------------
// K3: fused g-vectors + R reduction + Ivec/Hvec assembly
// ---------------------------------------------------------------------------
__global__ __launch_bounds__(128) void k_hv(
    const float* __restrict__ input, float* __restrict__ ws)
{
  __shared__ float gwS[80], pcS[24];
  const int tid=threadIdx.x;
  const int cx = blockIdx.x*128 + tid;
  if (tid<80) gwS[tid]=ws[O_GETW+tid];
  if (tid<24) pcS[tid]=ws[O_POPC+tid];
  __syncthreads();
  float inp[WN];
  #pragma unroll
  for (int k=0;k<WN;k++) inp[k]=input[k*ISZ+cx];
  float g[5];
  #pragma unroll
  for (int t=0;t<5;t++){
    float a=0.f;
    #pragma unroll
    for (int k=0;k<WN;k++) a += gwS[t*16+k]*inp[k];
    g[t]=a;
    ws[O_G + t*ISZ + cx]=a;
  }
  float R[7];
  #pragma unroll
  for (int k=0;k<7;k++){
    float a=0.f;
    for (int y=0;y<32;y++) a += ws[O_RPART + (size_t)(y*7+k)*ISZ + cx];
    R[k]=a;
  }
  ws[O_IVEC + cx]=R[0];
  ws[O_HVEC + cx]=R[1];
  #pragma unroll
  for (int d=1;d<ND;d++){
    ws[O_IVEC + d*ISZ + cx] = g[d-1];
    float h = R[1+d];
    for (int t=0;t<=d-2;t++) h += pcS[d*4+t]*g[t];
    ws[O_HVEC + d*ISZ + cx] = h;
  }
}

// ---------------------------------------------------------------------------
// Batched matvec body: Y[d][row] = sum_k W[row][k]*X[d][k] + bias
// ---------------------------------------------------------------------------
__device__ __forceinline__ void mv_body(
    const float* __restrict__ W, int ldw,
    const float* __restrict__ Xg, const float* __restrict__ bias,
    float* __restrict__ Y, int bb, float* xs)
{
  for (int idx=threadIdx.x; idx<6*ISZ; idx+=1024) xs[idx]=Xg[idx];
  __syncthreads();
  const int wv=threadIdx.x>>6, ln=threadIdx.x&63;
  const int row = bb*16+wv;
  const float* wr = W + (size_t)row*ldw;
  float a[6]={0,0,0,0,0,0};
  #pragma unroll 4
  for (int k=ln*4; k<ISZ; k+=256){
    float4 w4 = *(const float4*)(wr + k);
    #pragma unroll
    for (int d=0; d<6; d++){
      float4 x4 = *(const float4*)(xs + d*ISZ + k);
      a[d] += w4.x*x4.x + w4.y*x4.y + w4.z*x4.z + w4.w*x4.w;
    }
  }
  #pragma unroll
  for (int d=0;d<6;d++){
    float v = a[d];
    #pragma unroll
    for (int o=32;o>0;o>>=1) v += __shfl_down(v,o);
    if (ln==0) Y[d*ISZ+row] = v + (bias? bias[row] : 0.f);
  }
}

// kin-half1(IVEC)->Z1 | ff(HVEC)->YFF | kin-half2(HVEC)->Z2 — one launch
__global__ __launch_bounds__(1024) void k_matvecA(
    const float* __restrict__ ff_w, const float* __restrict__ ff_b,
    const float* __restrict__ kin_w, const float* __restrict__ kin_b,
    float* __restrict__ ws)
{
  __shared__ float xs[6*ISZ];
  const int task = blockIdx.x >> 8, bb = blockIdx.x & 255;
  if (task==0)      mv_body(kin_w,     2*ISZ, ws+O_IVEC, kin_b,   ws+O_Z1,  bb, xs);
  else if (task==1) mv_body(ff_w,      ISZ,   ws+O_HVEC, ff_b,    ws+O_YFF, bb, xs);
  else              mv_body(kin_w+ISZ, 2*ISZ, ws+O_HVEC, nullptr, ws+O_Z2,  bb, xs);
}

// kouth(NEWINP)->YH | kouti(NEWINP)->YI — one launch
__global__ __launch_bounds__(1024) void k_matvecB(
    const float* __restrict__ kouth_w, const float* __restrict__ kouth_b,
    const float* __restrict__ kouti_w, const float* __restrict__ kouti_b,
    float* __restrict__ ws)
{
  __shared__ float xs[6*ISZ];
  const int task = blockIdx.x >> 8, bb = blockIdx.x & 255;
  if (task==0) mv_body(kouth_w, ISZ, ws+O_NEWINP, kouth_b, ws+O_YH, bb, xs);
  else         mv_body(kouti_w, ISZ, ws+O_NEWINP, kouti_b, ws+O_YI, bb, xs);
}

// ---------------------------------------------------------------------------
// S1: perp_pred KLD, softmax(z)->new_inp, gate   (6 blocks)
// ---------------------------------------------------------------------------
__global__ __launch_bounds__(1024) void k_s1(
    const float* __restrict__ gate_w, const float* __restrict__ gate_b,
    float* __restrict__ ws)
{
  __shared__ float sm[96];
  const int d=blockIdx.x, tid=threadIdx.x;
  const float* y  = ws+O_YFF + d*ISZ;
  const float* z1 = ws+O_Z1  + d*ISZ;
  const float* z2 = ws+O_Z2  + d*ISZ;
  const float* iv = ws+O_IVEC+ d*ISZ;
  const float* hv = ws+O_HVEC+ d*ISZ;

  float yv[4], zv[4], ivv[4], hvv[4];
  #pragma unroll
  for (int i=0;i<4;i++){
    int cx=tid+i*1024;
    yv[i]=y[cx]; zv[i]=z1[cx]+z2[cx]; ivv[i]=iv[cx]; hvv[i]=hv[cx];
  }
  float mx[2]={-FLT_MAX,-FLT_MAX};
  #pragma unroll
  for (int i=0;i<4;i++){ mx[0]=fmaxf(mx[0],yv[i]); mx[1]=fmaxf(mx[1],zv[i]); }
  bRedMaxN<2>(mx,sm);

  float s5[5]={0,0,0,0,0};   // se(y), se2(z), sum(y), sum(iv), sum(hv)
  #pragma unroll
  for (int i=0;i<4;i++){
    s5[0]+=expf(yv[i]-mx[0]); s5[1]+=expf(zv[i]-mx[1]);
    s5[2]+=yv[i]; s5[3]+=ivv[i]; s5[4]+=hvv[i];
  }
  bRedSumN<5>(s5,sm);
  const float lse = mx[0]+logf(s5[0]);
  const float sP  = s5[2] - (float)ISZ*lse + (float)ISZ*EPSF;
  const float sQ  = s5[3] + (float)ISZ*EPSF;
  const float inv2= 1.f/s5[1];

  float kk[1]={0.f};
  #pragma unroll
  for (int i=0;i<4;i++){
    int cx=tid+i*1024;
    ws[O_NEWINP + d*ISZ + cx] = expf(zv[i]-mx[1])*inv2;
    float ph=((yv[i]-lse)+EPSF)/sP;
    float qh=(ivv[i]+EPSF)/sQ;
    kk[0]+=ph*(logf(ph)-logf(qh));
  }
  bRedSumN<1>(kk,sm);

  if (tid==0){
    float pp=kk[0];
    float a0=gate_w[0]*pp+gate_b[0];
    float a1=gate_w[1]*pp+gate_b[1];
    float mg=fmaxf(a0,a1);
    float e0=expf(a0-mg), e1=expf(a1-mg);
    float g1=e1/(e0+e1);
    if (s5[4]==0.f) g1=0.f;
    else if (s5[3]==0.f) g1=1.f;
    ws[O_SCAL+d]=pp; ws[O_SCAL+6+d]=g1;
    ws[O_SCAL+24+d]=sQ;
    ws[O_SCAL+30+d]=s5[4]+(float)ISZ*EPSF;
  }
}

// ---------------------------------------------------------------------------
// S2: both output KLDs, batched  (6 blocks)
// ---------------------------------------------------------------------------
__global__ __launch_bounds__(1024) void k_s2(float* __restrict__ ws)
{
  __shared__ float sm[96];
  const int d=blockIdx.x, tid=threadIdx.x;
  const float* yh = ws+O_YH  + d*ISZ;
  const float* yi = ws+O_YI  + d*ISZ;
  const float* hv = ws+O_HVEC+ d*ISZ;
  const float* iv = ws+O_IVEC+ d*ISZ;

  float yhv[4], yiv[4], hvv[4], ivv[4];
  #pragma unroll
  for (int i=0;i<4;i++){
    int cx=tid+i*1024;
    yhv[i]=yh[cx]; yiv[i]=yi[cx]; hvv[i]=hv[cx]; ivv[i]=iv[cx];
  }
  float mx[2]={-FLT_MAX,-FLT_MAX};
  #pragma unroll
  for (int i=0;i<4;i++){ mx[0]=fmaxf(mx[0],yhv[i]); mx[1]=fmaxf(mx[1],yiv[i]); }
  bRedMaxN<2>(mx,sm);
  float se[2]={0,0};
  #pragma unroll
  for (int i=0;i<4;i++){ se[0]+=expf(yhv[i]-mx[0]); se[1]+=expf(yiv[i]-mx[1]); }
  bRedSumN<2>(se,sm);
  const float invh=1.f/se[0], invi=1.f/se[1];
  const float spc = 1.f + (float)ISZ*EPSF;   // sum(softmax)+ISZ*eps
  const float sqh = ws[O_SCAL+30+d], sqi = ws[O_SCAL+24+d];

  float kk[2]={0,0};
  #pragma unroll
  for (int i=0;i<4;i++){
    float ph=(expf(yhv[i]-mx[0])*invh+EPSF)/spc;
    float qh=(hvv[i]+EPSF)/sqh;
    kk[0]+=ph*(logf(ph)-logf(qh));
    float pi=(expf(yiv[i]-mx[1])*invi+EPSF)/spc;
    float qi=(ivv[i]+EPSF)/sqi;
    kk[1]+=pi*(logf(pi)-logf(qi));
  }
  bRedSumN<2>(kk,sm);
  if (tid==0) ws[O_SCAL+12+d] = ws[O_SCAL+d] + 0.5f*(kk[0]+kk[1]);
}

// ---------------------------------------------------------------------------
// FIN: w chain + resperp + new_sp + new_ip  (1 block)
// ---------------------------------------------------------------------------
__global__ __launch_bounds__(1024) void k_fin(float* __restrict__ ws,
                                              float* __restrict__ out)
{
  __shared__ float sm[32];
  __shared__ float wsh[ND];
  const int tid=threadIdx.x;
  if (tid==0){
    const float* g1=ws+O_SCAL+6; const float* pp=ws+O_SCAL+12; const float* av=ws+O_AVAIL;
    float wl[ND]; wl[0]=g1[0];
    for (int i=1;i<ND;i++) wl[i]=(1.f-wl[i-1])*g1[i]*av[i];
    float s=0.f; for (int i=0;i<ND;i++) s+=wl[i];
    float rp=0.f;
    for (int i=0;i<ND;i++){ float wn=wl[i]/s; wsh[i]=wn; rp+=wn*pp[i]; }
    out[0]=rp;
  }
  __syncthreads();
  float w[ND];
  #pragma unroll
  for (int dd=0;dd<ND;dd++) w[dd]=wsh[dd];
  const float* sptr=ws+O_SPTR;
  float snl[2], ms=0.f;
  #pragma unroll
  for (int jj=0;jj<2;jj++){
    int j=tid+jj*1024;
    float sn=0.f;
    #pragma unroll
    for (int dd=0;dd<ND;dd++) sn += w[dd]*sptr[dd*HH+j];
    snl[jj]=sn; ms+=sn;
  }
  float t[1]={ms};
  bRedSumN<1>(t,sm);
  float ssum=t[0];
  #pragma unroll
  for (int jj=0;jj<2;jj++){
    int j=tid+jj*1024;
    out[1 + (size_t)HH*ISZ + j] = (ssum>0.f)? snl[jj]/ssum : snl[jj];
  }
  if (tid==0){
    const float* iptr=ws+O_IPTR;
    float ipn[WN+1]; float is=0.f;
    for (int k=0;k<=WN;k++){
      float a=0.f;
      for (int dd=0;dd<ND;dd++) a += w[dd]*iptr[dd*16+k];
      ipn[k]=a; is+=a;
    }
    size_t base = 1 + (size_t)HH*ISZ + HH;
    for (int k=0;k<=WN;k++) out[base+k] = (is>0.f)? ipn[k]/is : ipn[k];
  }
}

// ---------------------------------------------------------------------------
// STACK_OUT: out = Mw[j]*stack + sum_v Ceff[j][v]*V[v]  (Mw/Ceff inline)
// ---------------------------------------------------------------------------
__global__ __launch_bounds__(256) void k_stack_out(
    const float* __restrict__ stk, const float* __restrict__ ws,
    float* __restrict__ out)
{
  __shared__ float Vt[10*1024];
  __shared__ float wsh[ND];
  __shared__ float mwS[8];
  __shared__ float ceS[8][10];
  const int tid=threadIdx.x;
  const int c0 = blockIdx.x*1024;
  const int j0 = blockIdx.y*8;

  if (tid==0){
    const float* g1=ws+O_SCAL+6; const float* av=ws+O_AVAIL;
    float wl[ND]; wl[0]=g1[0];
    for (int i=1;i<ND;i++) wl[i]=(1.f-wl[i-1])*g1[i]*av[i];
    float s=0.f; for (int i=0;i<ND;i++) s+=wl[i];
    for (int i=0;i<ND;i++) wsh[i]=wl[i]/s;
  }
  const float* V = ws+O_NEWINP;
  for (int idx=tid; idx<10*1024; idx+=256){
    int v=idx>>10, cc=idx&1023;
    Vt[idx] = V[v*ISZ + c0 + cc];
  }
  __syncthreads();
  if (tid<8){
    int j=j0+tid;
    float mw=0.f, ce[10]={0,0,0,0,0,0,0,0,0,0};
    for (int dd=0;dd<ND;dd++){
      float wd=wsh[dd];
      mw    += wd*ws[O_DFIN+dd*HH+j];
      ce[dd] = wd*ws[O_CNEW+dd*HH+j];
    }
    for (int t=0;t<4;t++){
      float a=0.f;
      for (int dd=t+2;dd<ND;dd++) a += wsh[dd]*ws[O_CFIN+(dd*4+t)*HH+j];
      ce[6+t]=a;
    }
    mwS[tid]=mw;
    for (int v=0;v<10;v++) ceS[tid][v]=ce[v];
  }
  __syncthreads();
  const int tx4 = tid*4;
  for (int r=0;r<8;r++){
    int j=j0+r;
    float mw = mwS[r];
    float4 sv = *(const float4*)(stk + (size_t)j*ISZ + c0 + tx4);
    float o0 = mw*sv.x, o1 = mw*sv.y, o2 = mw*sv.z, o3 = mw*sv.w;
    #pragma unroll
    for (int v=0;v<10;v++){
      const float* vr = Vt + v*1024 + tx4;
      float cv=ceS[r][v];
      o0 += cv*vr[0]; o1 += cv*vr[1]; o2 += cv*vr[2]; o3 += cv*vr[3];
    }
    float* op = out + 1 + (size_t)j*ISZ + c0 + tx4;
    op[0]=o0; op[1]=o1; op[2]=o2; op[3]=o3;
  }
}

extern "C" void kernel_launch(void* const* d_in, const int* in_sizes, int n_in,
                              void* d_out, int out_size, void* d_ws, size_t ws_size,
                              hipStream_t stream)
{
  (void)in_sizes; (void)n_in; (void)out_size; (void)ws_size;
  const float* input   = (const float*)d_in[0];
  const float* stack   = (const float*)d_in[1];
  const float* sp0     = (const float*)d_in[2];
  const float* ip0     = (const float*)d_in[3];
  const float* ff_w    = (const float*)d_in[4];
  const float* ff_b    = (const float*)d_in[5];
  const float* gate_w  = (const float*)d_in[6];
  const float* gate_b  = (const float*)d_in[7];
  const float* kin_w   = (const float*)d_in[8];
  const float* kin_b   = (const float*)d_in[9];
  const float* kouth_w = (const float*)d_in[10];
  const float* kouth_b = (const float*)d_in[11];
  const float* kouti_w = (const float*)d_in[12];
  const float* kouti_b = (const float*)d_in[13];
  float* out = (float*)d_out;
  float* ws  = (float*)d_ws;

  k_ptr_prep<<<ND,1024,0,stream>>>(sp0, ip0, ws);
  k_rowsum<<<dim3(16,32),256,0,stream>>>(stack, ws+O_WROW, ws+O_RPART);
  k_hv<<<32,128,0,stream>>>(input, ws);
  k_matvecA<<<768,1024,0,stream>>>(ff_w, ff_b, kin_w, kin_b, ws);
  k_s1<<<ND,1024,0,stream>>>(gate_w, gate_b, ws);
  k_matvecB<<<512,1024,0,stream>>>(kouth_w, kouth_b, kouti_w, kouti_b, ws);
  k_s2<<<ND,1024,0,stream>>>(ws);
  k_stack_out<<<dim3(4,256),256,0,stream>>>(stack, ws, out);
  k_fin<<<1,1024,0,stream>>>(ws, out);
}